// Round 1
// baseline (1025.254 us; speedup 1.0000x reference)
//
#include <hip/hip_runtime.h>
#include <hip/hip_bf16.h>
#include <float.h>

#define N_NODES 20000
#define N_EDGES 320000
#define ET      (N_EDGES + N_NODES)   // edges + self loops
#define DCH     512
#define INCH    55
#define OUTCH   49

// ---------------- CSR build (by dst) ----------------
__global__ void count_kernel(const int* __restrict__ ei, int* __restrict__ counts) {
    int e = blockIdx.x * blockDim.x + threadIdx.x;
    if (e >= ET) return;
    int d = (e < N_EDGES) ? ei[N_EDGES + e] : (e - N_EDGES);
    atomicAdd(&counts[d], 1);
}

__global__ void scan_kernel(const int* __restrict__ counts, int* __restrict__ row_ptr) {
    __shared__ int sdata[1024];
    const int n = N_NODES;
    int t = threadIdx.x;
    int per = (n + 1023) / 1024;               // 20
    int b = t * per, e = min(n, b + per);
    int sum = 0;
    for (int i = b; i < e; ++i) sum += counts[i];
    sdata[t] = sum;
    __syncthreads();
    for (int off = 1; off < 1024; off <<= 1) {
        int v = (t >= off) ? sdata[t - off] : 0;
        __syncthreads();
        sdata[t] += v;
        __syncthreads();
    }
    int run = (t == 0) ? 0 : sdata[t - 1];
    if (t == 0) row_ptr[0] = 0;
    for (int i = b; i < e; ++i) { run += counts[i]; row_ptr[i + 1] = run; }
}

__global__ void fill_kernel(const int* __restrict__ ei, const int* __restrict__ row_ptr,
                            int* __restrict__ cursor, int* __restrict__ esrc) {
    int e = blockIdx.x * blockDim.x + threadIdx.x;
    if (e >= ET) return;
    int s, d;
    if (e < N_EDGES) { s = ei[e]; d = ei[N_EDGES + e]; }
    else             { s = d = e - N_EDGES; }
    int pos = row_ptr[d] + atomicAdd(&cursor[d], 1);
    esrc[pos] = s;
}

// ---------------- fp32 tiled GEMM: C[M,N] = A[M,K]@B[K,N] + bias[N] ----------------
template<int BM, int BN, int BK>
__global__ __launch_bounds__(256) void gemm_bias(const float* __restrict__ A,
                                                 const float* __restrict__ B,
                                                 const float* __restrict__ bias,
                                                 float* __restrict__ C,
                                                 int M, int N, int K) {
    __shared__ float As[BK][BM + 4];
    __shared__ float Bs[BK][BN + 4];
    const int tid = threadIdx.x;
    const int tx = tid & 15, ty = tid >> 4;
    const int m0 = blockIdx.y * BM, n0 = blockIdx.x * BN;
    float acc[8][8] = {};
    for (int k0 = 0; k0 < K; k0 += BK) {
        for (int i = tid; i < BM * BK; i += 256) {
            int m = i / BK, kk = i % BK;
            int gm = m0 + m, gk = k0 + kk;
            As[kk][m] = (gm < M && gk < K) ? A[(size_t)gm * K + gk] : 0.f;
        }
        for (int i = tid; i < BK * BN; i += 256) {
            int kk = i / BN, nn = i % BN;
            int gk = k0 + kk, gn = n0 + nn;
            Bs[kk][nn] = (gk < K && gn < N) ? B[(size_t)gk * N + gn] : 0.f;
        }
        __syncthreads();
        #pragma unroll
        for (int kk = 0; kk < BK; ++kk) {
            const float4* arow = (const float4*)&As[kk][ty * 8];
            const float4* brow = (const float4*)&Bs[kk][tx * 8];
            float4 a0 = arow[0], a1 = arow[1];
            float4 b0 = brow[0], b1 = brow[1];
            float ra[8] = {a0.x, a0.y, a0.z, a0.w, a1.x, a1.y, a1.z, a1.w};
            float rb[8] = {b0.x, b0.y, b0.z, b0.w, b1.x, b1.y, b1.z, b1.w};
            #pragma unroll
            for (int i = 0; i < 8; ++i)
                #pragma unroll
                for (int j = 0; j < 8; ++j)
                    acc[i][j] += ra[i] * rb[j];
        }
        __syncthreads();
    }
    #pragma unroll
    for (int i = 0; i < 8; ++i) {
        int gm = m0 + ty * 8 + i;
        if (gm >= M) continue;
        #pragma unroll
        for (int j = 0; j < 8; ++j) {
            int gn = n0 + tx * 8 + j;
            if (gn < N) C[(size_t)gm * N + gn] = acc[i][j] + bias[gn];
        }
    }
}

// ---------------- fused GATv2 edge phase: one wave per dst node ----------------
// component layout per lane: c = 4*lane + 256*k (k=0,1), so half-wave h = (lane>>5)+2k
// owns one head per k; scores reduce within 32-lane halves only.
__global__ __launch_bounds__(256) void edge_agg(const int* __restrict__ row_ptr,
                                                const int* __restrict__ esrc,
                                                const float* __restrict__ xl,
                                                const float* __restrict__ xr,
                                                const float* __restrict__ att,
                                                const float* __restrict__ bias,
                                                float* __restrict__ out) {
    int wid = (blockIdx.x * 256 + threadIdx.x) >> 6;
    if (wid >= N_NODES) return;
    int lane = threadIdx.x & 63;

    const float4* xrv   = (const float4*)(xr + (size_t)wid * DCH);
    const float4* attv  = (const float4*)att;
    const float4* biasv = (const float4*)bias;
    float4 xr0 = xrv[lane], xr1 = xrv[lane + 64];
    float4 av0 = attv[lane], av1 = attv[lane + 64];

    float4 acc0 = {0.f, 0.f, 0.f, 0.f}, acc1 = {0.f, 0.f, 0.f, 0.f};
    float m0 = -FLT_MAX, m1 = -FLT_MAX, d0 = 0.f, d1 = 0.f;

    int beg = row_ptr[wid], end = row_ptr[wid + 1];
    for (int p = beg; p < end; ++p) {
        int s = esrc[p];
        const float4* xsv = (const float4*)(xl + (size_t)s * DCH);
        float4 a = xsv[lane], b = xsv[lane + 64];

        float t0 = a.x + xr0.x; t0 = t0 > 0.f ? t0 : 0.2f * t0;
        float t1 = a.y + xr0.y; t1 = t1 > 0.f ? t1 : 0.2f * t1;
        float t2 = a.z + xr0.z; t2 = t2 > 0.f ? t2 : 0.2f * t2;
        float t3 = a.w + xr0.w; t3 = t3 > 0.f ? t3 : 0.2f * t3;
        float p0 = t0 * av0.x + t1 * av0.y + t2 * av0.z + t3 * av0.w;

        t0 = b.x + xr1.x; t0 = t0 > 0.f ? t0 : 0.2f * t0;
        t1 = b.y + xr1.y; t1 = t1 > 0.f ? t1 : 0.2f * t1;
        t2 = b.z + xr1.z; t2 = t2 > 0.f ? t2 : 0.2f * t2;
        t3 = b.w + xr1.w; t3 = t3 > 0.f ? t3 : 0.2f * t3;
        float p1 = t0 * av1.x + t1 * av1.y + t2 * av1.z + t3 * av1.w;

        #pragma unroll
        for (int off = 16; off > 0; off >>= 1) {   // stays within each 32-lane half
            p0 += __shfl_xor(p0, off, 64);
            p1 += __shfl_xor(p1, off, 64);
        }

        // online softmax update, head k=0 for this lane
        float mn = fmaxf(m0, p0);
        float f  = __expf(m0 - mn), w = __expf(p0 - mn);
        d0 = d0 * f + w;
        acc0.x = acc0.x * f + w * a.x; acc0.y = acc0.y * f + w * a.y;
        acc0.z = acc0.z * f + w * a.z; acc0.w = acc0.w * f + w * a.w;
        m0 = mn;
        // head k=1
        mn = fmaxf(m1, p1);
        f  = __expf(m1 - mn); w = __expf(p1 - mn);
        d1 = d1 * f + w;
        acc1.x = acc1.x * f + w * b.x; acc1.y = acc1.y * f + w * b.y;
        acc1.z = acc1.z * f + w * b.z; acc1.w = acc1.w * f + w * b.w;
        m1 = mn;
    }

    float4 bb0 = biasv[lane], bb1 = biasv[lane + 64];
    float4 o0, o1;
    o0.x = acc0.x / d0 + bb0.x; o0.y = acc0.y / d0 + bb0.y;
    o0.z = acc0.z / d0 + bb0.z; o0.w = acc0.w / d0 + bb0.w;
    o1.x = acc1.x / d1 + bb1.x; o1.y = acc1.y / d1 + bb1.y;
    o1.z = acc1.z / d1 + bb1.z; o1.w = acc1.w / d1 + bb1.w;
    // ELU (alpha=1)
    o0.x = o0.x > 0.f ? o0.x : __expf(o0.x) - 1.f;
    o0.y = o0.y > 0.f ? o0.y : __expf(o0.y) - 1.f;
    o0.z = o0.z > 0.f ? o0.z : __expf(o0.z) - 1.f;
    o0.w = o0.w > 0.f ? o0.w : __expf(o0.w) - 1.f;
    o1.x = o1.x > 0.f ? o1.x : __expf(o1.x) - 1.f;
    o1.y = o1.y > 0.f ? o1.y : __expf(o1.y) - 1.f;
    o1.z = o1.z > 0.f ? o1.z : __expf(o1.z) - 1.f;
    o1.w = o1.w > 0.f ? o1.w : __expf(o1.w) - 1.f;

    float4* outv = (float4*)(out + (size_t)wid * DCH);
    outv[lane] = o0;
    outv[lane + 64] = o1;
}

// ---------------- launch ----------------
extern "C" void kernel_launch(void* const* d_in, const int* in_sizes, int n_in,
                              void* d_out, int out_size, void* d_ws, size_t ws_size,
                              hipStream_t stream) {
    const float* x     = (const float*)d_in[0];
    const int*   ei    = (const int*)d_in[1];
    const float* w1_l  = (const float*)d_in[2];
    const float* b1_l  = (const float*)d_in[3];
    const float* w1_r  = (const float*)d_in[4];
    const float* b1_r  = (const float*)d_in[5];
    const float* att1  = (const float*)d_in[6];
    const float* bias1 = (const float*)d_in[7];
    const float* w2_l  = (const float*)d_in[8];
    const float* b2_l  = (const float*)d_in[9];
    const float* w2_r  = (const float*)d_in[10];
    const float* b2_r  = (const float*)d_in[11];
    const float* att2  = (const float*)d_in[12];
    const float* bias2 = (const float*)d_in[13];
    const float* wcls  = (const float*)d_in[14];
    const float* bcls  = (const float*)d_in[15];
    float* out = (float*)d_out;

    char* ws = (char*)d_ws;
    float* xl = (float*)ws;                                  // N*D f32
    float* xr = xl + (size_t)N_NODES * DCH;                  // N*D f32
    float* h  = xr + (size_t)N_NODES * DCH;                  // N*D f32
    int* row_ptr = (int*)(h + (size_t)N_NODES * DCH);        // N+1
    int* cursor  = row_ptr + (N_NODES + 1);                  // N
    int* esrc    = cursor + N_NODES;                         // ET

    // CSR (identical for both layers)
    hipMemsetAsync(cursor, 0, N_NODES * sizeof(int), stream);
    count_kernel<<<(ET + 255) / 256, 256, 0, stream>>>(ei, cursor);
    scan_kernel<<<1, 1024, 0, stream>>>(cursor, row_ptr);
    hipMemsetAsync(cursor, 0, N_NODES * sizeof(int), stream);
    fill_kernel<<<(ET + 255) / 256, 256, 0, stream>>>(ei, row_ptr, cursor, esrc);

    dim3 blk(256);
    dim3 gD((DCH + 127) / 128, (N_NODES + 127) / 128);       // 4 x 157
    dim3 gC((OUTCH + 127) / 128, (N_NODES + 127) / 128);     // 1 x 157
    int eb = (N_NODES + 3) / 4;                              // 4 waves/block

    // layer 1
    gemm_bias<128, 128, 16><<<gD, blk, 0, stream>>>(x, w1_l, b1_l, xl, N_NODES, DCH, INCH);
    gemm_bias<128, 128, 16><<<gD, blk, 0, stream>>>(x, w1_r, b1_r, xr, N_NODES, DCH, INCH);
    edge_agg<<<eb, 256, 0, stream>>>(row_ptr, esrc, xl, xr, att1, bias1, h);
    // layer 2
    gemm_bias<128, 128, 16><<<gD, blk, 0, stream>>>(h, w2_l, b2_l, xl, N_NODES, DCH, DCH);
    gemm_bias<128, 128, 16><<<gD, blk, 0, stream>>>(h, w2_r, b2_r, xr, N_NODES, DCH, DCH);
    edge_agg<<<eb, 256, 0, stream>>>(row_ptr, esrc, xl, xr, att2, bias2, h);
    // classifier
    gemm_bias<128, 128, 16><<<gC, blk, 0, stream>>>(h, wcls, bcls, out, N_NODES, OUTCH, DCH);
}

// Round 2
// 391.195 us; speedup vs baseline: 2.6208x; 2.6208x over previous
//
#include <hip/hip_runtime.h>
#include <hip/hip_bf16.h>
#include <float.h>

#define N_NODES 20000
#define N_EDGES 320000
#define ET      (N_EDGES + N_NODES)   // edges + self loops
#define DCH     512
#define INCH    55
#define INCHP   64                     // K padded for layer-1 GEMM
#define OUTCH   49
#define OUTCHP  128                    // N padded for classifier GEMM

typedef _Float16 f16;
typedef _Float16 f16x8 __attribute__((ext_vector_type(8)));
typedef float    f32x4 __attribute__((ext_vector_type(4)));

#define GPTR(p) ((const __attribute__((address_space(1))) void*)(p))
#define LPTR(p) ((__attribute__((address_space(3))) void*)(p))

// ---------------- CSR build (by dst) ----------------
__global__ void count_kernel(const int* __restrict__ ei, int* __restrict__ counts) {
    int e = blockIdx.x * blockDim.x + threadIdx.x;
    if (e >= ET) return;
    int d = (e < N_EDGES) ? ei[N_EDGES + e] : (e - N_EDGES);
    atomicAdd(&counts[d], 1);
}

__global__ void scan_kernel(const int* __restrict__ counts, int* __restrict__ row_ptr) {
    __shared__ int sdata[1024];
    const int n = N_NODES;
    int t = threadIdx.x;
    int per = (n + 1023) / 1024;
    int b = t * per, e = min(n, b + per);
    int sum = 0;
    for (int i = b; i < e; ++i) sum += counts[i];
    sdata[t] = sum;
    __syncthreads();
    for (int off = 1; off < 1024; off <<= 1) {
        int v = (t >= off) ? sdata[t - off] : 0;
        __syncthreads();
        sdata[t] += v;
        __syncthreads();
    }
    int run = (t == 0) ? 0 : sdata[t - 1];
    if (t == 0) row_ptr[0] = 0;
    for (int i = b; i < e; ++i) { run += counts[i]; row_ptr[i + 1] = run; }
}

__global__ void fill_kernel(const int* __restrict__ ei, const int* __restrict__ row_ptr,
                            int* __restrict__ cursor, int* __restrict__ esrc) {
    int e = blockIdx.x * blockDim.x + threadIdx.x;
    if (e >= ET) return;
    int s, d;
    if (e < N_EDGES) { s = ei[e]; d = ei[N_EDGES + e]; }
    else             { s = d = e - N_EDGES; }
    int pos = row_ptr[d] + atomicAdd(&cursor[d], 1);
    esrc[pos] = s;
}

// ---------------- dtype conversion ----------------
__global__ void conv_x(const float* __restrict__ x, f16* __restrict__ o) {
    int i = blockIdx.x * 256 + threadIdx.x;         // over N_NODES*INCHP
    if (i >= N_NODES * INCHP) return;
    int r = i >> 6, c = i & 63;
    o[i] = (c < INCH) ? (f16)x[r * INCH + c] : (f16)0.f;
}

// w [K][N] fp32 -> o [Np][Kp] fp16 (transposed, zero-padded)
__global__ void conv_wT(const float* __restrict__ w, f16* __restrict__ o,
                        int K, int N, int Kp, int Np) {
    int i = blockIdx.x * 256 + threadIdx.x;
    if (i >= Kp * Np) return;
    int n = i / Kp, k = i % Kp;
    o[i] = (k < K && n < N) ? (f16)w[(size_t)k * N + n] : (f16)0.f;
}

// ---------------- fp16 MFMA GEMM: C[M,Nv] = A[M,Ka] @ BT[Np,Ka]^T + bias ----------
// m97 structure: 128x128 tile, BK=64, 4 waves (2x2), global_load_lds width 16,
// 2-barrier K-loop, linear LDS (known 16-way conflict on frag reads; accepted R2).
template<int OUT_F16>
__global__ __launch_bounds__(256) void gemm_f16(const f16* __restrict__ A,
                                                const f16* __restrict__ BT,
                                                const float* __restrict__ bias,
                                                void* __restrict__ Cout,
                                                int M, int Ka, int Nv, int ldc) {
    __shared__ __align__(16) f16 As[128][64];
    __shared__ __align__(16) f16 Bs[128][64];
    const int tid = threadIdx.x;
    const int w = tid >> 6, lane = tid & 63;
    const int m0 = blockIdx.y * 128, n0 = blockIdx.x * 128;
    const int wr = (w >> 1) * 64, wc = (w & 1) * 64;
    const int lrow = lane & 15, lk = (lane >> 4) * 8;

    f32x4 acc[4][4] = {};

    for (int k0 = 0; k0 < Ka; k0 += 64) {
        #pragma unroll
        for (int i = 0; i < 4; ++i) {
            int idx = tid + 256 * i;
            int row = idx >> 3, col = (idx & 7) * 8;
            int gm = m0 + row; gm = gm < M ? gm : M - 1;   // clamp: tail rows duplicate
            const f16* gp = A + (size_t)gm * Ka + k0 + col;
            f16* lp = &As[0][0] + (size_t)(w * 64 + 256 * i) * 8;  // wave-uniform base
            __builtin_amdgcn_global_load_lds(GPTR(gp), LPTR(lp), 16, 0, 0);
        }
        #pragma unroll
        for (int i = 0; i < 4; ++i) {
            int idx = tid + 256 * i;
            int row = idx >> 3, col = (idx & 7) * 8;
            const f16* gp = BT + (size_t)(n0 + row) * Ka + k0 + col;
            f16* lp = &Bs[0][0] + (size_t)(w * 64 + 256 * i) * 8;
            __builtin_amdgcn_global_load_lds(GPTR(gp), LPTR(lp), 16, 0, 0);
        }
        __syncthreads();
        #pragma unroll
        for (int kk = 0; kk < 64; kk += 32) {
            f16x8 af[4], bf[4];
            #pragma unroll
            for (int m = 0; m < 4; ++m)
                af[m] = *(const f16x8*)&As[wr + m * 16 + lrow][kk + lk];
            #pragma unroll
            for (int n = 0; n < 4; ++n)
                bf[n] = *(const f16x8*)&Bs[wc + n * 16 + lrow][kk + lk];
            #pragma unroll
            for (int m = 0; m < 4; ++m)
                #pragma unroll
                for (int n = 0; n < 4; ++n)
                    acc[m][n] = __builtin_amdgcn_mfma_f32_16x16x32_f16(af[m], bf[n], acc[m][n], 0, 0, 0);
        }
        __syncthreads();
    }

    // epilogue: C/D map col=lane&15, row=(lane>>4)*4+r (m89-verified, dtype-indep)
    const int orow = (lane >> 4) * 4, ocol = lane & 15;
    #pragma unroll
    for (int m = 0; m < 4; ++m) {
        #pragma unroll
        for (int r = 0; r < 4; ++r) {
            int gm = m0 + wr + m * 16 + orow + r;
            if (gm >= M) continue;
            #pragma unroll
            for (int n = 0; n < 4; ++n) {
                int gn = n0 + wc + n * 16 + ocol;
                if (gn >= Nv) continue;
                float v = acc[m][n][r] + bias[gn];
                if (OUT_F16) ((f16*)Cout)[(size_t)gm * ldc + gn] = (f16)v;
                else         ((float*)Cout)[(size_t)gm * ldc + gn] = v;
            }
        }
    }
}

// ---------------- fused GATv2 edge phase: one wave per dst node, fp16 I/O -------
// lane owns channels c = lane*8 .. +7; head = lane>>4; score reduce = 4 shuffles
// within each 16-lane group.
__global__ __launch_bounds__(256) void edge_agg16(const int* __restrict__ row_ptr,
                                                  const int* __restrict__ esrc,
                                                  const f16* __restrict__ xl,
                                                  const f16* __restrict__ xr,
                                                  const float* __restrict__ att,
                                                  const float* __restrict__ bias,
                                                  f16* __restrict__ out) {
    int wid = (blockIdx.x * 256 + threadIdx.x) >> 6;
    if (wid >= N_NODES) return;
    int lane = threadIdx.x & 63;

    f16x8 xr8 = ((const f16x8*)(xr + (size_t)wid * DCH))[lane];
    float xrf[8], atf[8];
    #pragma unroll
    for (int j = 0; j < 8; ++j) xrf[j] = (float)xr8[j];
    const float4* av = (const float4*)(att + lane * 8);   // att flat [4][128]=[512]
    float4 a0 = av[0], a1 = av[1];
    atf[0]=a0.x; atf[1]=a0.y; atf[2]=a0.z; atf[3]=a0.w;
    atf[4]=a1.x; atf[5]=a1.y; atf[6]=a1.z; atf[7]=a1.w;

    float acc[8] = {};
    float mrun = -FLT_MAX, den = 0.f;

    int beg = row_ptr[wid], end = row_ptr[wid + 1];
    for (int p = beg; p < end; ++p) {
        int s = esrc[p];
        f16x8 a8 = ((const f16x8*)(xl + (size_t)s * DCH))[lane];
        float af[8];
        float sc = 0.f;
        #pragma unroll
        for (int j = 0; j < 8; ++j) {
            af[j] = (float)a8[j];
            float t = af[j] + xrf[j];
            t = t > 0.f ? t : 0.2f * t;
            sc += t * atf[j];
        }
        sc += __shfl_xor(sc, 1, 64);
        sc += __shfl_xor(sc, 2, 64);
        sc += __shfl_xor(sc, 4, 64);
        sc += __shfl_xor(sc, 8, 64);
        float mn = fmaxf(mrun, sc);
        float f = __expf(mrun - mn), wgt = __expf(sc - mn);
        den = den * f + wgt;
        #pragma unroll
        for (int j = 0; j < 8; ++j) acc[j] = acc[j] * f + wgt * af[j];
        mrun = mn;
    }

    const float4* bv = (const float4*)(bias + lane * 8);
    float4 b0 = bv[0], b1 = bv[1];
    float bf[8] = {b0.x,b0.y,b0.z,b0.w,b1.x,b1.y,b1.z,b1.w};
    float inv = 1.f / den;
    f16x8 o8;
    #pragma unroll
    for (int j = 0; j < 8; ++j) {
        float v = acc[j] * inv + bf[j];
        v = v > 0.f ? v : __expf(v) - 1.f;   // ELU
        o8[j] = (f16)v;
    }
    ((f16x8*)(out + (size_t)wid * DCH))[lane] = o8;
}

// ---------------- launch ----------------
extern "C" void kernel_launch(void* const* d_in, const int* in_sizes, int n_in,
                              void* d_out, int out_size, void* d_ws, size_t ws_size,
                              hipStream_t stream) {
    const float* x     = (const float*)d_in[0];
    const int*   ei    = (const int*)d_in[1];
    const float* w1_l  = (const float*)d_in[2];
    const float* b1_l  = (const float*)d_in[3];
    const float* w1_r  = (const float*)d_in[4];
    const float* b1_r  = (const float*)d_in[5];
    const float* att1  = (const float*)d_in[6];
    const float* bias1 = (const float*)d_in[7];
    const float* w2_l  = (const float*)d_in[8];
    const float* b2_l  = (const float*)d_in[9];
    const float* w2_r  = (const float*)d_in[10];
    const float* b2_r  = (const float*)d_in[11];
    const float* att2  = (const float*)d_in[12];
    const float* bias2 = (const float*)d_in[13];
    const float* wcls  = (const float*)d_in[14];
    const float* bcls  = (const float*)d_in[15];
    float* out = (float*)d_out;

    char* ws = (char*)d_ws;
    f16* x_h  = (f16*)ws;                                   // N*64
    f16* w1lT = x_h  + (size_t)N_NODES * INCHP;             // 512*64
    f16* w1rT = w1lT + (size_t)DCH * INCHP;
    f16* w2lT = w1rT + (size_t)DCH * INCHP;                 // 512*512
    f16* w2rT = w2lT + (size_t)DCH * DCH;
    f16* wcT  = w2rT + (size_t)DCH * DCH;                   // 128*512
    f16* xl   = wcT  + (size_t)OUTCHP * DCH;                // N*512
    f16* xr   = xl   + (size_t)N_NODES * DCH;
    f16* h    = xr   + (size_t)N_NODES * DCH;
    int* row_ptr = (int*)(h + (size_t)N_NODES * DCH);
    int* cursor  = row_ptr + (N_NODES + 1);
    int* esrc    = cursor + N_NODES;

    // CSR (same graph both layers)
    hipMemsetAsync(cursor, 0, N_NODES * sizeof(int), stream);
    count_kernel<<<(ET + 255) / 256, 256, 0, stream>>>(ei, cursor);
    scan_kernel<<<1, 1024, 0, stream>>>(cursor, row_ptr);
    hipMemsetAsync(cursor, 0, N_NODES * sizeof(int), stream);
    fill_kernel<<<(ET + 255) / 256, 256, 0, stream>>>(ei, row_ptr, cursor, esrc);

    // dtype prep
    conv_x<<<(N_NODES * INCHP + 255) / 256, 256, 0, stream>>>(x, x_h);
    conv_wT<<<(DCH * INCHP + 255) / 256, 256, 0, stream>>>(w1_l, w1lT, INCH, DCH, INCHP, DCH);
    conv_wT<<<(DCH * INCHP + 255) / 256, 256, 0, stream>>>(w1_r, w1rT, INCH, DCH, INCHP, DCH);
    conv_wT<<<(DCH * DCH + 255) / 256, 256, 0, stream>>>(w2_l, w2lT, DCH, DCH, DCH, DCH);
    conv_wT<<<(DCH * DCH + 255) / 256, 256, 0, stream>>>(w2_r, w2rT, DCH, DCH, DCH, DCH);
    conv_wT<<<(OUTCHP * DCH + 255) / 256, 256, 0, stream>>>(wcls, wcT, DCH, OUTCH, DCH, OUTCHP);

    dim3 blk(256);
    dim3 gD(DCH / 128, (N_NODES + 127) / 128);              // 4 x 157
    dim3 gC(1, (N_NODES + 127) / 128);                      // 1 x 157
    int eb = (N_NODES + 3) / 4;

    // layer 1 (K=64 padded)
    gemm_f16<1><<<gD, blk, 0, stream>>>(x_h, w1lT, b1_l, xl, N_NODES, INCHP, DCH, DCH);
    gemm_f16<1><<<gD, blk, 0, stream>>>(x_h, w1rT, b1_r, xr, N_NODES, INCHP, DCH, DCH);
    edge_agg16<<<eb, blk, 0, stream>>>(row_ptr, esrc, xl, xr, att1, bias1, h);
    // layer 2 (K=512)
    gemm_f16<1><<<gD, blk, 0, stream>>>(h, w2lT, b2_l, xl, N_NODES, DCH, DCH, DCH);
    gemm_f16<1><<<gD, blk, 0, stream>>>(h, w2rT, b2_r, xr, N_NODES, DCH, DCH, DCH);
    edge_agg16<<<eb, blk, 0, stream>>>(row_ptr, esrc, xl, xr, att2, bias2, h);
    // classifier (N padded to 128, fp32 out)
    gemm_f16<0><<<gC, blk, 0, stream>>>(h, wcT, bcls, out, N_NODES, DCH, OUTCH, OUTCH);
}

// Round 3
// 323.409 us; speedup vs baseline: 3.1701x; 1.2096x over previous
//
#include <hip/hip_runtime.h>
#include <hip/hip_bf16.h>
#include <float.h>

#define N_NODES 20000
#define N_EDGES 320000
#define ET      (N_EDGES + N_NODES)   // edges + self loops
#define DCH     512
#define D2      1024                   // fused l|r width
#define INCH    55
#define INCHP   64
#define OUTCH   49
#define OUTCHP  128

typedef _Float16 f16;
typedef _Float16 f16x2 __attribute__((ext_vector_type(2)));
typedef _Float16 f16x8 __attribute__((ext_vector_type(8)));
typedef float    f32x4 __attribute__((ext_vector_type(4)));

#define GPTR(p) ((const __attribute__((address_space(1))) void*)(p))
#define LPTR(p) ((__attribute__((address_space(3))) void*)(p))

// ---------------- CSR build (by dst) ----------------
__global__ void count_kernel(const int* __restrict__ ei, int* __restrict__ counts) {
    int e = blockIdx.x * blockDim.x + threadIdx.x;
    if (e >= ET) return;
    int d = (e < N_EDGES) ? ei[N_EDGES + e] : (e - N_EDGES);
    atomicAdd(&counts[d], 1);
}

__global__ void scan_kernel(const int* __restrict__ counts, int* __restrict__ row_ptr) {
    __shared__ int sdata[1024];
    const int n = N_NODES;
    int t = threadIdx.x;
    int per = (n + 1023) / 1024;
    int b = t * per, e = min(n, b + per);
    int sum = 0;
    for (int i = b; i < e; ++i) sum += counts[i];
    sdata[t] = sum;
    __syncthreads();
    for (int off = 1; off < 1024; off <<= 1) {
        int v = (t >= off) ? sdata[t - off] : 0;
        __syncthreads();
        sdata[t] += v;
        __syncthreads();
    }
    int run = (t == 0) ? 0 : sdata[t - 1];
    if (t == 0) row_ptr[0] = 0;
    for (int i = b; i < e; ++i) { run += counts[i]; row_ptr[i + 1] = run; }
}

__global__ void fill_kernel(const int* __restrict__ ei, const int* __restrict__ row_ptr,
                            int* __restrict__ cursor, int* __restrict__ esrc) {
    int e = blockIdx.x * blockDim.x + threadIdx.x;
    if (e >= ET) return;
    int s, d;
    if (e < N_EDGES) { s = ei[e]; d = ei[N_EDGES + e]; }
    else             { s = d = e - N_EDGES; }
    int pos = row_ptr[d] + atomicAdd(&cursor[d], 1);
    esrc[pos] = s;
}

// ---------------- dtype conversion ----------------
__global__ void conv_x(const float* __restrict__ x, f16* __restrict__ o) {
    int i = blockIdx.x * 256 + threadIdx.x;
    if (i >= N_NODES * INCHP) return;
    int r = i >> 6, c = i & 63;
    o[i] = (c < INCH) ? (f16)x[r * INCH + c] : (f16)0.f;
}

// w [K][N] fp32 -> o [Np][Kp] fp16 (transposed, zero-padded)
__global__ void conv_wT(const float* __restrict__ w, f16* __restrict__ o,
                        int K, int N, int Kp, int Np) {
    int i = blockIdx.x * 256 + threadIdx.x;
    if (i >= Kp * Np) return;
    int n = i / Kp, k = i % Kp;
    o[i] = (k < K && n < N) ? (f16)w[(size_t)k * N + n] : (f16)0.f;
}

// ---------------- fp16 MFMA GEMM (m97 structure, XCD-swizzled) ----------------
// C[M,Nv] = A[M,Ka] @ BT[*,Ka]^T + bias ; DUAL: bias = gn<512 ? bl[gn] : br[gn-512]
template<int OUT_F16, int DUAL>
__global__ __launch_bounds__(256) void gemm_f16(const f16* __restrict__ A,
                                                const f16* __restrict__ BT,
                                                const float* __restrict__ bl,
                                                const float* __restrict__ br,
                                                void* __restrict__ Cout,
                                                int M, int Ka, int Nv, int ldc) {
    __shared__ __align__(16) f16 As[128][64];
    __shared__ __align__(16) f16 Bs[128][64];
    const int tid = threadIdx.x;
    const int w = tid >> 6, lane = tid & 63;
    // bijective XCD swizzle (T1): consecutive dispatch ids round-robin XCDs;
    // give each XCD a contiguous run of tiles (contiguous A row-panels).
    int nbx = gridDim.x;
    int nwg = nbx * gridDim.y;
    int bid = blockIdx.y * nbx + blockIdx.x;
    if ((nwg & 7) == 0) bid = (bid & 7) * (nwg >> 3) + (bid >> 3);
    const int m0 = (bid / nbx) * 128, n0 = (bid % nbx) * 128;
    const int wr = (w >> 1) * 64, wc = (w & 1) * 64;
    const int lrow = lane & 15, lk = (lane >> 4) * 8;

    f32x4 acc[4][4] = {};

    for (int k0 = 0; k0 < Ka; k0 += 64) {
        #pragma unroll
        for (int i = 0; i < 4; ++i) {
            int idx = tid + 256 * i;
            int row = idx >> 3, col = (idx & 7) * 8;
            int gm = m0 + row; gm = gm < M ? gm : M - 1;   // tail rows duplicate
            const f16* gp = A + (size_t)gm * Ka + k0 + col;
            f16* lp = &As[0][0] + (size_t)(w * 64 + 256 * i) * 8;  // wave-uniform base
            __builtin_amdgcn_global_load_lds(GPTR(gp), LPTR(lp), 16, 0, 0);
        }
        #pragma unroll
        for (int i = 0; i < 4; ++i) {
            int idx = tid + 256 * i;
            int row = idx >> 3, col = (idx & 7) * 8;
            const f16* gp = BT + (size_t)(n0 + row) * Ka + k0 + col;
            f16* lp = &Bs[0][0] + (size_t)(w * 64 + 256 * i) * 8;
            __builtin_amdgcn_global_load_lds(GPTR(gp), LPTR(lp), 16, 0, 0);
        }
        __syncthreads();
        #pragma unroll
        for (int kk = 0; kk < 64; kk += 32) {
            f16x8 af[4], bf[4];
            #pragma unroll
            for (int m = 0; m < 4; ++m)
                af[m] = *(const f16x8*)&As[wr + m * 16 + lrow][kk + lk];
            #pragma unroll
            for (int n = 0; n < 4; ++n)
                bf[n] = *(const f16x8*)&Bs[wc + n * 16 + lrow][kk + lk];
            #pragma unroll
            for (int m = 0; m < 4; ++m)
                #pragma unroll
                for (int n = 0; n < 4; ++n)
                    acc[m][n] = __builtin_amdgcn_mfma_f32_16x16x32_f16(af[m], bf[n], acc[m][n], 0, 0, 0);
        }
        __syncthreads();
    }

    const int orow = (lane >> 4) * 4, ocol = lane & 15;   // C/D map (m89)
    #pragma unroll
    for (int m = 0; m < 4; ++m) {
        #pragma unroll
        for (int r = 0; r < 4; ++r) {
            int gm = m0 + wr + m * 16 + orow + r;
            if (gm >= M) continue;
            #pragma unroll
            for (int n = 0; n < 4; ++n) {
                int gn = n0 + wc + n * 16 + ocol;
                if (gn >= Nv) continue;
                float bv = DUAL ? (gn < DCH ? bl[gn] : br[gn - DCH]) : bl[gn];
                float v = acc[m][n][r] + bv;
                if (OUT_F16) ((f16*)Cout)[(size_t)gm * ldc + gn] = (f16)v;
                else         ((float*)Cout)[(size_t)gm * ldc + gn] = v;
            }
        }
    }
}

// ---------------- fused GATv2 edge phase v3 ----------------
// one wave per dst; lane owns 8 ch (head = lane>>4); packed-f16 score via
// v_dot2_f32_f16; 2-edge unroll; defer-max THR=8; edge ids preloaded+shfl.
__global__ __launch_bounds__(256) void edge_agg3(const int* __restrict__ row_ptr,
                                                 const int* __restrict__ esrc,
                                                 const f16* __restrict__ xlr,
                                                 const float* __restrict__ att,
                                                 const float* __restrict__ bias,
                                                 f16* __restrict__ out) {
    int wid = (blockIdx.x * 256 + threadIdx.x) >> 6;
    if (wid >= N_NODES) return;
    int lane = threadIdx.x & 63;

    union { f16x8 v; f16x2 p[4]; } uxr;
    uxr.v = *(const f16x8*)(xlr + (size_t)wid * D2 + DCH + lane * 8);
    const float4* av = (const float4*)(att + lane * 8);
    float4 a0 = av[0], a1 = av[1];
    f16x2 at2[4];
    at2[0] = f16x2{(f16)a0.x, (f16)a0.y}; at2[1] = f16x2{(f16)a0.z, (f16)a0.w};
    at2[2] = f16x2{(f16)a1.x, (f16)a1.y}; at2[3] = f16x2{(f16)a1.z, (f16)a1.w};
    const f16x2 k02 = {(f16)0.2f, (f16)0.2f};

    int beg = row_ptr[wid], end = row_ptr[wid + 1];
    int deg = end - beg;
    int pre = (lane < deg) ? esrc[beg + lane] : 0;

    float acc[8] = {};
    float mrun = -FLT_MAX, den = 0.f;

    int dmain = deg < 64 ? deg : 64;
    int p = 0;
    for (; p + 1 < dmain; p += 2) {
        int s0 = __shfl(pre, p, 64), s1 = __shfl(pre, p + 1, 64);
        union { f16x8 v; f16x2 q[4]; } u0, u1;
        u0.v = *(const f16x8*)(xlr + (size_t)s0 * D2 + lane * 8);
        u1.v = *(const f16x8*)(xlr + (size_t)s1 * D2 + lane * 8);
        float sc0 = 0.f, sc1 = 0.f;
        #pragma unroll
        for (int j = 0; j < 4; ++j) {
            f16x2 t0 = u0.q[j] + uxr.p[j];
            f16x2 t1 = u1.q[j] + uxr.p[j];
            f16x2 l0 = __builtin_elementwise_max(t0, t0 * k02);   // leaky relu
            f16x2 l1 = __builtin_elementwise_max(t1, t1 * k02);
            sc0 = __builtin_amdgcn_fdot2(l0, at2[j], sc0, false);
            sc1 = __builtin_amdgcn_fdot2(l1, at2[j], sc1, false);
        }
        #pragma unroll
        for (int o = 8; o >= 1; o >>= 1) {
            sc0 += __shfl_xor(sc0, o, 64);
            sc1 += __shfl_xor(sc1, o, 64);
        }
        float mx = fmaxf(sc0, sc1);
        if (__any(mx > mrun + 8.f)) {        // defer-max (T13)
            float mn = fmaxf(mrun, mx);
            float f = __expf(mrun - mn);
            den *= f;
            #pragma unroll
            for (int j = 0; j < 8; ++j) acc[j] *= f;
            mrun = mn;
        }
        float w0 = __expf(sc0 - mrun), w1 = __expf(sc1 - mrun);
        den += w0 + w1;
        #pragma unroll
        for (int j = 0; j < 8; ++j)
            acc[j] += w0 * (float)u0.v[j] + w1 * (float)u1.v[j];
    }
    for (; p < deg; ++p) {                   // odd tail + deg>64 fallback
        int s = (p < 64) ? __shfl(pre, p, 64) : esrc[beg + p];
        union { f16x8 v; f16x2 q[4]; } u0;
        u0.v = *(const f16x8*)(xlr + (size_t)s * D2 + lane * 8);
        float sc0 = 0.f;
        #pragma unroll
        for (int j = 0; j < 4; ++j) {
            f16x2 t0 = u0.q[j] + uxr.p[j];
            f16x2 l0 = __builtin_elementwise_max(t0, t0 * k02);
            sc0 = __builtin_amdgcn_fdot2(l0, at2[j], sc0, false);
        }
        #pragma unroll
        for (int o = 8; o >= 1; o >>= 1) sc0 += __shfl_xor(sc0, o, 64);
        if (__any(sc0 > mrun + 8.f)) {
            float mn = fmaxf(mrun, sc0);
            float f = __expf(mrun - mn);
            den *= f;
            #pragma unroll
            for (int j = 0; j < 8; ++j) acc[j] *= f;
            mrun = mn;
        }
        float w0 = __expf(sc0 - mrun);
        den += w0;
        #pragma unroll
        for (int j = 0; j < 8; ++j) acc[j] += w0 * (float)u0.v[j];
    }

    const float4* bv = (const float4*)(bias + lane * 8);
    float4 b0 = bv[0], b1 = bv[1];
    float bf[8] = {b0.x, b0.y, b0.z, b0.w, b1.x, b1.y, b1.z, b1.w};
    float inv = 1.f / den;
    f16x8 o8;
    #pragma unroll
    for (int j = 0; j < 8; ++j) {
        float v = acc[j] * inv + bf[j];
        v = v > 0.f ? v : __expf(v) - 1.f;   // ELU
        o8[j] = (f16)v;
    }
    *(f16x8*)(out + (size_t)wid * DCH + lane * 8) = o8;
}

// ---------------- launch ----------------
extern "C" void kernel_launch(void* const* d_in, const int* in_sizes, int n_in,
                              void* d_out, int out_size, void* d_ws, size_t ws_size,
                              hipStream_t stream) {
    const float* x     = (const float*)d_in[0];
    const int*   ei    = (const int*)d_in[1];
    const float* w1_l  = (const float*)d_in[2];
    const float* b1_l  = (const float*)d_in[3];
    const float* w1_r  = (const float*)d_in[4];
    const float* b1_r  = (const float*)d_in[5];
    const float* att1  = (const float*)d_in[6];
    const float* bias1 = (const float*)d_in[7];
    const float* w2_l  = (const float*)d_in[8];
    const float* b2_l  = (const float*)d_in[9];
    const float* w2_r  = (const float*)d_in[10];
    const float* b2_r  = (const float*)d_in[11];
    const float* att2  = (const float*)d_in[12];
    const float* bias2 = (const float*)d_in[13];
    const float* wcls  = (const float*)d_in[14];
    const float* bcls  = (const float*)d_in[15];
    float* out = (float*)d_out;

    char* ws = (char*)d_ws;
    f16* x_h = (f16*)ws;                                    // N*64
    f16* w1T = x_h + (size_t)N_NODES * INCHP;               // 1024*64  (l|r)
    f16* w2T = w1T + (size_t)D2 * INCHP;                    // 1024*512 (l|r)
    f16* wcT = w2T + (size_t)D2 * DCH;                      // 128*512
    f16* xlr = wcT + (size_t)OUTCHP * DCH;                  // N*1024
    f16* h   = xlr + (size_t)N_NODES * D2;                  // N*512
    int* row_ptr = (int*)(h + (size_t)N_NODES * DCH);
    int* cursor  = row_ptr + (N_NODES + 1);
    int* esrc    = cursor + N_NODES;

    // CSR (same graph both layers)
    hipMemsetAsync(cursor, 0, N_NODES * sizeof(int), stream);
    count_kernel<<<(ET + 255) / 256, 256, 0, stream>>>(ei, cursor);
    scan_kernel<<<1, 1024, 0, stream>>>(cursor, row_ptr);
    hipMemsetAsync(cursor, 0, N_NODES * sizeof(int), stream);
    fill_kernel<<<(ET + 255) / 256, 256, 0, stream>>>(ei, row_ptr, cursor, esrc);

    // dtype prep (weights transposed+padded, l|r concatenated)
    conv_x<<<(N_NODES * INCHP + 255) / 256, 256, 0, stream>>>(x, x_h);
    conv_wT<<<(DCH * INCHP + 255) / 256, 256, 0, stream>>>(w1_l, w1T, INCH, DCH, INCHP, DCH);
    conv_wT<<<(DCH * INCHP + 255) / 256, 256, 0, stream>>>(w1_r, w1T + (size_t)DCH * INCHP, INCH, DCH, INCHP, DCH);
    conv_wT<<<(DCH * DCH + 255) / 256, 256, 0, stream>>>(w2_l, w2T, DCH, DCH, DCH, DCH);
    conv_wT<<<(DCH * DCH + 255) / 256, 256, 0, stream>>>(w2_r, w2T + (size_t)DCH * DCH, DCH, DCH, DCH, DCH);
    conv_wT<<<(OUTCHP * DCH + 255) / 256, 256, 0, stream>>>(wcls, wcT, DCH, OUTCH, DCH, OUTCHP);

    dim3 blk(256);
    dim3 gD(D2 / 128, (N_NODES + 127) / 128);               // 8 x 157 (nwg%8==0)
    dim3 gC(1, (N_NODES + 127) / 128);
    int eb = (N_NODES + 3) / 4;

    // layer 1 (fused l|r, K=64)
    gemm_f16<1, 1><<<gD, blk, 0, stream>>>(x_h, w1T, b1_l, b1_r, xlr, N_NODES, INCHP, D2, D2);
    edge_agg3<<<eb, blk, 0, stream>>>(row_ptr, esrc, xlr, att1, bias1, h);
    // layer 2 (fused l|r, K=512)
    gemm_f16<1, 1><<<gD, blk, 0, stream>>>(h, w2T, b2_l, b2_r, xlr, N_NODES, DCH, D2, D2);
    edge_agg3<<<eb, blk, 0, stream>>>(row_ptr, esrc, xlr, att2, bias2, h);
    // classifier (N padded 128, fp32 out)
    gemm_f16<0, 0><<<gC, blk, 0, stream>>>(h, wcT, bcls, bcls, out, N_NODES, DCH, OUTCH, OUTCH);
}

// Round 4
// 321.429 us; speedup vs baseline: 3.1897x; 1.0062x over previous
//
#include <hip/hip_runtime.h>
#include <hip/hip_bf16.h>
#include <float.h>
#include <math.h>

#define N_NODES 20000
#define N_EDGES 320000
#define ET      (N_EDGES + N_NODES)   // edges + self loops
#define DCH     512
#define D2      1024                   // fused l|r width
#define INCH    55
#define INCHP   64
#define OUTCH   49
#define OUTCHP  128

typedef _Float16 f16;
typedef _Float16 f16x2 __attribute__((ext_vector_type(2)));
typedef _Float16 f16x8 __attribute__((ext_vector_type(8)));
typedef float    f32x4 __attribute__((ext_vector_type(4)));

#define GPTR(p) ((const __attribute__((address_space(1))) void*)(p))
#define LPTR(p) ((__attribute__((address_space(3))) void*)(p))

// ---------------- CSR build (by dst) ----------------
__global__ void count_kernel(const int* __restrict__ ei, int* __restrict__ counts) {
    int e = blockIdx.x * blockDim.x + threadIdx.x;
    if (e >= ET) return;
    int d = (e < N_EDGES) ? ei[N_EDGES + e] : (e - N_EDGES);
    atomicAdd(&counts[d], 1);
}

__global__ void scan_kernel(const int* __restrict__ counts, int* __restrict__ row_ptr) {
    __shared__ int sdata[1024];
    const int n = N_NODES;
    int t = threadIdx.x;
    int per = (n + 1023) / 1024;
    int b = t * per, e = min(n, b + per);
    int sum = 0;
    for (int i = b; i < e; ++i) sum += counts[i];
    sdata[t] = sum;
    __syncthreads();
    for (int off = 1; off < 1024; off <<= 1) {
        int v = (t >= off) ? sdata[t - off] : 0;
        __syncthreads();
        sdata[t] += v;
        __syncthreads();
    }
    int run = (t == 0) ? 0 : sdata[t - 1];
    if (t == 0) row_ptr[0] = 0;
    for (int i = b; i < e; ++i) { run += counts[i]; row_ptr[i + 1] = run; }
}

__global__ void fill_kernel(const int* __restrict__ ei, const int* __restrict__ row_ptr,
                            int* __restrict__ cursor, int* __restrict__ esrc) {
    int e = blockIdx.x * blockDim.x + threadIdx.x;
    if (e >= ET) return;
    int s, d;
    if (e < N_EDGES) { s = ei[e]; d = ei[N_EDGES + e]; }
    else             { s = d = e - N_EDGES; }
    int pos = row_ptr[d] + atomicAdd(&cursor[d], 1);
    esrc[pos] = s;
}

// ---------------- dtype conversion ----------------
__global__ void conv_x(const float* __restrict__ x, f16* __restrict__ o) {
    int i = blockIdx.x * 256 + threadIdx.x;
    if (i >= N_NODES * INCHP) return;
    int r = i >> 6, c = i & 63;
    o[i] = (c < INCH) ? (f16)x[r * INCH + c] : (f16)0.f;
}

// LDS-tiled transpose: w [K][N] f32 -> o [Np][Kp] f16, zero-padded.
// 64x64 tile per block; both global phases coalesced. Kp,Np multiples of 64.
__global__ __launch_bounds__(256) void conv_wTt(const float* __restrict__ w, f16* __restrict__ o,
                                                int K, int N, int Np) {
    __shared__ f16 tile[64][66];           // row stride 132B = 33 words -> conflict-free cols
    int k0 = blockIdx.y * 64, n0 = blockIdx.x * 64;
    int t = threadIdx.x;
    int Kp = gridDim.y * 64;
    #pragma unroll
    for (int r = 0; r < 16; ++r) {
        int kl = (t >> 6) + r * 4, nl = t & 63;
        int gk = k0 + kl, gn = n0 + nl;
        tile[kl][nl] = (gk < K && gn < N) ? (f16)w[(size_t)gk * N + gn] : (f16)0.f;
    }
    __syncthreads();
    #pragma unroll
    for (int r = 0; r < 16; ++r) {
        int kl = t & 63, nl = (t >> 6) + r * 4;
        o[(size_t)(n0 + nl) * Kp + k0 + kl] = tile[kl][nl];
    }
}

// ---------------- fp16 MFMA GEMM (m97 structure + T2 XOR swizzle, XCD swizzle) ----
// C[M,Nv] = A[M,Ka] @ BT[*,Ka]^T + bias ; DUAL: bias = gn<512 ? bl[gn] : br[gn-512]
// T2 (rule 21): gload_lds dest is linear; the SOURCE col-group is pre-swizzled
// cg' = cg ^ (row&7), and reads apply the same XOR -> 16-way conflict -> <=2-way.
template<int OUT_F16, int DUAL>
__global__ __launch_bounds__(256) void gemm_f16(const f16* __restrict__ A,
                                                const f16* __restrict__ BT,
                                                const float* __restrict__ bl,
                                                const float* __restrict__ br,
                                                void* __restrict__ Cout,
                                                int M, int Ka, int Nv, int ldc) {
    __shared__ __align__(16) f16 As[128][64];
    __shared__ __align__(16) f16 Bs[128][64];
    const int tid = threadIdx.x;
    const int w = tid >> 6, lane = tid & 63;
    int nbx = gridDim.x;
    int nwg = nbx * gridDim.y;
    int bid = blockIdx.y * nbx + blockIdx.x;
    if ((nwg & 7) == 0) bid = (bid & 7) * (nwg >> 3) + (bid >> 3);   // XCD swizzle (T1)
    const int m0 = (bid / nbx) * 128, n0 = (bid % nbx) * 128;
    const int wr = (w >> 1) * 64, wc = (w & 1) * 64;
    const int lrow = lane & 15, lk = lane >> 4;        // lk = col-group index (0..3)
    const int sw = lrow & 7;                           // read-side XOR key

    f32x4 acc[4][4] = {};

    for (int k0 = 0; k0 < Ka; k0 += 64) {
        #pragma unroll
        for (int i = 0; i < 4; ++i) {
            int idx = tid + 256 * i;
            int row = idx >> 3;
            int cg  = (idx & 7) ^ (row & 7);           // pre-swizzled source col-group
            int gm = m0 + row; gm = gm < M ? gm : M - 1;
            const f16* gp = A + (size_t)gm * Ka + k0 + cg * 8;
            f16* lp = &As[0][0] + (size_t)(w * 64 + 256 * i) * 8;   // linear wave-uniform dest
            __builtin_amdgcn_global_load_lds(GPTR(gp), LPTR(lp), 16, 0, 0);
        }
        #pragma unroll
        for (int i = 0; i < 4; ++i) {
            int idx = tid + 256 * i;
            int row = idx >> 3;
            int cg  = (idx & 7) ^ (row & 7);
            const f16* gp = BT + (size_t)(n0 + row) * Ka + k0 + cg * 8;
            f16* lp = &Bs[0][0] + (size_t)(w * 64 + 256 * i) * 8;
            __builtin_amdgcn_global_load_lds(GPTR(gp), LPTR(lp), 16, 0, 0);
        }
        __syncthreads();
        #pragma unroll
        for (int kk = 0; kk < 64; kk += 32) {
            f16x8 af[4], bf[4];
            #pragma unroll
            for (int m = 0; m < 4; ++m)
                af[m] = *(const f16x8*)&As[wr + m * 16 + lrow][(((kk >> 3) + lk) ^ sw) * 8];
            #pragma unroll
            for (int n = 0; n < 4; ++n)
                bf[n] = *(const f16x8*)&Bs[wc + n * 16 + lrow][(((kk >> 3) + lk) ^ sw) * 8];
            #pragma unroll
            for (int m = 0; m < 4; ++m)
                #pragma unroll
                for (int n = 0; n < 4; ++n)
                    acc[m][n] = __builtin_amdgcn_mfma_f32_16x16x32_f16(af[m], bf[n], acc[m][n], 0, 0, 0);
        }
        __syncthreads();
    }

    const int orow = (lane >> 4) * 4, ocol = lane & 15;   // C/D map (m89)
    #pragma unroll
    for (int m = 0; m < 4; ++m) {
        #pragma unroll
        for (int r = 0; r < 4; ++r) {
            int gm = m0 + wr + m * 16 + orow + r;
            if (gm >= M) continue;
            #pragma unroll
            for (int n = 0; n < 4; ++n) {
                int gn = n0 + wc + n * 16 + ocol;
                if (gn >= Nv) continue;
                float bv = DUAL ? (gn < DCH ? bl[gn] : br[gn - DCH]) : bl[gn];
                float v = acc[m][n][r] + bv;
                if (OUT_F16) ((f16*)Cout)[(size_t)gm * ldc + gn] = (f16)v;
                else         ((float*)Cout)[(size_t)gm * ldc + gn] = v;
            }
        }
    }
}

// ---------------- fused GATv2 edge phase v4: TWO nodes per wave ----------------
// Each wave runs two independent online-softmax chains (nodes 2w, 2w+1) ->
// 2 gathers in flight, interleaved reduce/exp/update chains. Lane owns 8 ch
// (head = lane>>4); score reduce = 4 shfl_xor within 16-lane groups.
// Invalid edge slots get score=-inf (weight 0). Defer-max THR=8 (T13).
__global__ __launch_bounds__(256) void edge_agg4(const int* __restrict__ row_ptr,
                                                 const int* __restrict__ esrc,
                                                 const f16* __restrict__ xlr,
                                                 const float* __restrict__ att,
                                                 const float* __restrict__ bias,
                                                 f16* __restrict__ out) {
    int wv = (blockIdx.x * 256 + threadIdx.x) >> 6;
    int n0 = wv * 2;
    if (n0 >= N_NODES) return;
    int n1 = n0 + 1;                       // N_NODES even -> always valid
    int lane = threadIdx.x & 63;

    union U8 { f16x8 v; f16x2 q[4]; };
    U8 xr0, xr1;
    xr0.v = *(const f16x8*)(xlr + (size_t)n0 * D2 + DCH + lane * 8);
    xr1.v = *(const f16x8*)(xlr + (size_t)n1 * D2 + DCH + lane * 8);
    const float4* av = (const float4*)(att + lane * 8);
    float4 a0 = av[0], a1 = av[1];
    f16x2 at2[4] = { f16x2{(f16)a0.x, (f16)a0.y}, f16x2{(f16)a0.z, (f16)a0.w},
                     f16x2{(f16)a1.x, (f16)a1.y}, f16x2{(f16)a1.z, (f16)a1.w} };
    const f16x2 k02 = {(f16)0.2f, (f16)0.2f};

    int beg0 = row_ptr[n0], deg0 = row_ptr[n0 + 1] - beg0;
    int beg1 = row_ptr[n1], deg1 = row_ptr[n1 + 1] - beg1;
    int pre0 = (lane < deg0) ? esrc[beg0 + lane] : 0;
    int pre1 = (lane < deg1) ? esrc[beg1 + lane] : 0;

    float acc0[8] = {}, acc1[8] = {};
    float m0 = -FLT_MAX, m1 = -FLT_MAX, d0 = 0.f, d1 = 0.f;

    int dmax = deg0 > deg1 ? deg0 : deg1;
    int dcap = dmax < 64 ? dmax : 64;
    for (int p = 0; p < dcap; ++p) {
        int s0 = __shfl(pre0, p, 64);      // lanes >= deg hold 0 -> safe row
        int s1 = __shfl(pre1, p, 64);
        U8 u0, u1;
        u0.v = *(const f16x8*)(xlr + (size_t)s0 * D2 + lane * 8);
        u1.v = *(const f16x8*)(xlr + (size_t)s1 * D2 + lane * 8);
        float sc0 = 0.f, sc1 = 0.f;
        #pragma unroll
        for (int j = 0; j < 4; ++j) {
            f16x2 t0 = u0.q[j] + xr0.q[j];
            f16x2 t1 = u1.q[j] + xr1.q[j];
            f16x2 l0 = __builtin_elementwise_max(t0, t0 * k02);
            f16x2 l1 = __builtin_elementwise_max(t1, t1 * k02);
            sc0 = __builtin_amdgcn_fdot2(l0, at2[j], sc0, false);
            sc1 = __builtin_amdgcn_fdot2(l1, at2[j], sc1, false);
        }
        #pragma unroll
        for (int o = 8; o >= 1; o >>= 1) {
            sc0 += __shfl_xor(sc0, o, 64);
            sc1 += __shfl_xor(sc1, o, 64);
        }
        if (p >= deg0) sc0 = -INFINITY;
        if (p >= deg1) sc1 = -INFINITY;
        if (__any(sc0 > m0 + 8.f)) {       // defer-max (T13)
            float mn = fmaxf(m0, sc0);
            float f = __expf(m0 - mn);
            d0 *= f;
            #pragma unroll
            for (int j = 0; j < 8; ++j) acc0[j] *= f;
            m0 = mn;
        }
        float w0 = __expf(sc0 - m0);
        d0 += w0;
        #pragma unroll
        for (int j = 0; j < 8; ++j) acc0[j] += w0 * (float)u0.v[j];
        if (__any(sc1 > m1 + 8.f)) {
            float mn = fmaxf(m1, sc1);
            float f = __expf(m1 - mn);
            d1 *= f;
            #pragma unroll
            for (int j = 0; j < 8; ++j) acc1[j] *= f;
            m1 = mn;
        }
        float w1 = __expf(sc1 - m1);
        d1 += w1;
        #pragma unroll
        for (int j = 0; j < 8; ++j) acc1[j] += w1 * (float)u1.v[j];
    }
    // rare tails: deg > 64
    for (int p = 64; p < deg0; ++p) {
        int s = esrc[beg0 + p];
        U8 u0; u0.v = *(const f16x8*)(xlr + (size_t)s * D2 + lane * 8);
        float sc0 = 0.f;
        #pragma unroll
        for (int j = 0; j < 4; ++j) {
            f16x2 t0 = u0.q[j] + xr0.q[j];
            f16x2 l0 = __builtin_elementwise_max(t0, t0 * k02);
            sc0 = __builtin_amdgcn_fdot2(l0, at2[j], sc0, false);
        }
        #pragma unroll
        for (int o = 8; o >= 1; o >>= 1) sc0 += __shfl_xor(sc0, o, 64);
        if (__any(sc0 > m0 + 8.f)) {
            float mn = fmaxf(m0, sc0);
            float f = __expf(m0 - mn);
            d0 *= f;
            #pragma unroll
            for (int j = 0; j < 8; ++j) acc0[j] *= f;
            m0 = mn;
        }
        float w0 = __expf(sc0 - m0);
        d0 += w0;
        #pragma unroll
        for (int j = 0; j < 8; ++j) acc0[j] += w0 * (float)u0.v[j];
    }
    for (int p = 64; p < deg1; ++p) {
        int s = esrc[beg1 + p];
        U8 u1; u1.v = *(const f16x8*)(xlr + (size_t)s * D2 + lane * 8);
        float sc1 = 0.f;
        #pragma unroll
        for (int j = 0; j < 4; ++j) {
            f16x2 t1 = u1.q[j] + xr1.q[j];
            f16x2 l1 = __builtin_elementwise_max(t1, t1 * k02);
            sc1 = __builtin_amdgcn_fdot2(l1, at2[j], sc1, false);
        }
        #pragma unroll
        for (int o = 8; o >= 1; o >>= 1) sc1 += __shfl_xor(sc1, o, 64);
        if (__any(sc1 > m1 + 8.f)) {
            float mn = fmaxf(m1, sc1);
            float f = __expf(m1 - mn);
            d1 *= f;
            #pragma unroll
            for (int j = 0; j < 8; ++j) acc1[j] *= f;
            m1 = mn;
        }
        float w1 = __expf(sc1 - m1);
        d1 += w1;
        #pragma unroll
        for (int j = 0; j < 8; ++j) acc1[j] += w1 * (float)u1.v[j];
    }

    const float4* bv = (const float4*)(bias + lane * 8);
    float4 b0 = bv[0], b1 = bv[1];
    float bf[8] = {b0.x, b0.y, b0.z, b0.w, b1.x, b1.y, b1.z, b1.w};
    float i0 = 1.f / d0, i1 = 1.f / d1;
    f16x8 o0, o1;
    #pragma unroll
    for (int j = 0; j < 8; ++j) {
        float v0 = acc0[j] * i0 + bf[j];
        float v1 = acc1[j] * i1 + bf[j];
        v0 = v0 > 0.f ? v0 : __expf(v0) - 1.f;   // ELU
        v1 = v1 > 0.f ? v1 : __expf(v1) - 1.f;
        o0[j] = (f16)v0;
        o1[j] = (f16)v1;
    }
    *(f16x8*)(out + (size_t)n0 * DCH + lane * 8) = o0;
    *(f16x8*)(out + (size_t)n1 * DCH + lane * 8) = o1;
}

// ---------------- launch ----------------
extern "C" void kernel_launch(void* const* d_in, const int* in_sizes, int n_in,
                              void* d_out, int out_size, void* d_ws, size_t ws_size,
                              hipStream_t stream) {
    const float* x     = (const float*)d_in[0];
    const int*   ei    = (const int*)d_in[1];
    const float* w1_l  = (const float*)d_in[2];
    const float* b1_l  = (const float*)d_in[3];
    const float* w1_r  = (const float*)d_in[4];
    const float* b1_r  = (const float*)d_in[5];
    const float* att1  = (const float*)d_in[6];
    const float* bias1 = (const float*)d_in[7];
    const float* w2_l  = (const float*)d_in[8];
    const float* b2_l  = (const float*)d_in[9];
    const float* w2_r  = (const float*)d_in[10];
    const float* b2_r  = (const float*)d_in[11];
    const float* att2  = (const float*)d_in[12];
    const float* bias2 = (const float*)d_in[13];
    const float* wcls  = (const float*)d_in[14];
    const float* bcls  = (const float*)d_in[15];
    float* out = (float*)d_out;

    char* ws = (char*)d_ws;
    f16* x_h = (f16*)ws;                                    // N*64
    f16* w1T = x_h + (size_t)N_NODES * INCHP;               // 1024*64  (l|r)
    f16* w2T = w1T + (size_t)D2 * INCHP;                    // 1024*512 (l|r)
    f16* wcT = w2T + (size_t)D2 * DCH;                      // 128*512
    f16* xlr = wcT + (size_t)OUTCHP * DCH;                  // N*1024
    f16* h   = xlr + (size_t)N_NODES * D2;                  // N*512
    int* row_ptr = (int*)(h + (size_t)N_NODES * DCH);
    int* cursor  = row_ptr + (N_NODES + 1);
    int* esrc    = cursor + N_NODES;

    // CSR (same graph both layers)
    hipMemsetAsync(cursor, 0, N_NODES * sizeof(int), stream);
    count_kernel<<<(ET + 255) / 256, 256, 0, stream>>>(ei, cursor);
    scan_kernel<<<1, 1024, 0, stream>>>(cursor, row_ptr);
    hipMemsetAsync(cursor, 0, N_NODES * sizeof(int), stream);
    fill_kernel<<<(ET + 255) / 256, 256, 0, stream>>>(ei, row_ptr, cursor, esrc);

    // dtype prep (coalesced LDS-tiled transpose, l|r concatenated)
    conv_x<<<(N_NODES * INCHP + 255) / 256, 256, 0, stream>>>(x, x_h);
    conv_wTt<<<dim3(8, 1), 256, 0, stream>>>(w1_l, w1T, INCH, DCH, DCH);
    conv_wTt<<<dim3(8, 1), 256, 0, stream>>>(w1_r, w1T + (size_t)DCH * INCHP, INCH, DCH, DCH);
    conv_wTt<<<dim3(8, 8), 256, 0, stream>>>(w2_l, w2T, DCH, DCH, DCH);
    conv_wTt<<<dim3(8, 8), 256, 0, stream>>>(w2_r, w2T + (size_t)DCH * DCH, DCH, DCH, DCH);
    conv_wTt<<<dim3(2, 8), 256, 0, stream>>>(wcls, wcT, DCH, OUTCH, OUTCHP);

    dim3 blk(256);
    dim3 gD(D2 / 128, (N_NODES + 127) / 128);               // 8 x 157 (nwg%8==0)
    dim3 gC(1, (N_NODES + 127) / 128);
    int eb = (N_NODES / 2 + 3) / 4;                         // 2 nodes per wave

    // layer 1 (fused l|r, K=64)
    gemm_f16<1, 1><<<gD, blk, 0, stream>>>(x_h, w1T, b1_l, b1_r, xlr, N_NODES, INCHP, D2, D2);
    edge_agg4<<<eb, blk, 0, stream>>>(row_ptr, esrc, xlr, att1, bias1, h);
    // layer 2 (fused l|r, K=512)
    gemm_f16<1, 1><<<gD, blk, 0, stream>>>(h, w2T, b2_l, b2_r, xlr, N_NODES, DCH, D2, D2);
    edge_agg4<<<eb, blk, 0, stream>>>(row_ptr, esrc, xlr, att2, bias2, h);
    // classifier (N padded 128, fp32 out)
    gemm_f16<0, 0><<<gC, blk, 0, stream>>>(h, wcT, bcls, bcls, out, N_NODES, DCH, OUTCH, OUTCH);
}